// Round 1
// baseline (2405.034 us; speedup 1.0000x reference)
//
#include <hip/hip_runtime.h>

#define DD 64
#define HC 384   // 2*D*L = hcat columns
#define SS 32

// ---------------- edge aggregation: thread = (edge, 4 channels) ----------------
__global__ __launch_bounds__(256) void agg_kernel(
    const float* __restrict__ h, const float* __restrict__ ew,
    const int* __restrict__ ei, float* __restrict__ agg, int E)
{
  int gid = blockIdx.x * 256 + threadIdx.x;
  int e = gid >> 4;
  if (e >= E) return;
  int q = (gid & 15) * 4;          // channel quad
  int s = ei[e];
  int d = ei[E + e];
  float w = ew[e];
  const float4 hv = *(const float4*)(h + (size_t)s * DD + q);
  float* ap = agg + (size_t)d * DD + q;
  atomicAdd(ap + 0, w * hv.x);
  atomicAdd(ap + 1, w * hv.y);
  atomicAdd(ap + 2, w * hv.z);
  atomicAdd(ap + 3, w * hv.w);
}

// ---------------- per-node GIN MLP + masked add-pool ----------------
// Block = 256 thr = 4 waves; each wave owns 64 nodes. LDS transpose with XOR
// swizzle: word (r, c) lives at r*64 + ((c + r) & 63)  -> all phases 2-way
// bank aliasing (free on gfx950).
__global__ __launch_bounds__(256) void node_kernel(
    const float* __restrict__ h, const float* __restrict__ agg,
    const float* __restrict__ W1, const float* __restrict__ b1,
    const float* __restrict__ gamma, const float* __restrict__ beta,
    const float* __restrict__ bnm, const float* __restrict__ bnv,
    const float* __restrict__ W2, const float* __restrict__ b2,
    const float* __restrict__ epsv, const float* __restrict__ pmask,
    const int* __restrict__ batch, float* __restrict__ hout,
    float* __restrict__ hcat, int layer, int N)
{
  __shared__ float tile_s[4][DD * DD];   // 64 KB total
  const int wave = threadIdx.x >> 6;
  const int lane = threadIdx.x & 63;
  float* tile = tile_s[wave];
  const int n0 = blockIdx.x * 256 + wave * 64;
  const float eps1 = 1.0f + epsv[layer];
  const float* W1l = W1 + layer * DD * DD;
  const float* W2l = W2 + layer * DD * DD;

  // phase 1: stage z = (1+eps)*h + agg  (coalesced reads; lane = channel)
  for (int r = 0; r < 64; ++r) {
    int n = n0 + r;
    float v = 0.0f;
    if (n < N) {
      size_t idx = (size_t)n * DD + lane;
      v = fmaf(eps1, h[idx], agg[idx]);
    }
    tile[r * DD + ((lane + r) & 63)] = v;
  }
  __syncthreads();

  // phase 2: lane = node (n0+lane).  GEMM1: t[c] = sum_k z[k] * W1[k][c]
  float t[DD];
  #pragma unroll
  for (int c = 0; c < DD; ++c) t[c] = 0.0f;
  for (int k = 0; k < DD; ++k) {
    float zk = tile[lane * DD + ((k + lane) & 63)];
    #pragma unroll
    for (int c = 0; c < DD; ++c)
      t[c] = fmaf(zk, W1l[k * DD + c], t[c]);   // W uniform -> scalar loads
  }
  // BN(eval) + ReLU, write z2 back into own LDS row
  #pragma unroll
  for (int c = 0; c < DD; ++c) {
    float A = gamma[layer * DD + c] * rsqrtf(bnv[layer * DD + c] + 1e-5f);
    float B = fmaf(b1[layer * DD + c] - bnm[layer * DD + c], A,
                   beta[layer * DD + c]);
    tile[lane * DD + ((c + lane) & 63)] = fmaxf(fmaf(t[c], A, B), 0.0f);
  }
  // GEMM2: t[c] = sum_k z2[k] * W2[k][c]
  #pragma unroll
  for (int c = 0; c < DD; ++c) t[c] = 0.0f;
  for (int k = 0; k < DD; ++k) {
    float zk = tile[lane * DD + ((k + lane) & 63)];
    #pragma unroll
    for (int c = 0; c < DD; ++c)
      t[c] = fmaf(zk, W2l[k * DD + c], t[c]);
  }
  // + b2, ReLU -> h_new into LDS row
  #pragma unroll
  for (int c = 0; c < DD; ++c)
    tile[lane * DD + ((c + lane) & 63)] =
        fmaxf(t[c] + b2[layer * DD + c], 0.0f);
  __syncthreads();

  // phase 3: coalesced store (lane = channel) + run-length pooled atomicAdd
  float accp = 0.0f;
  int gcur = -1;
  for (int r = 0; r < 64; ++r) {
    int n = n0 + r;
    if (n >= N) break;
    float v = tile[r * DD + ((lane + r) & 63)];
    hout[(size_t)n * DD + lane] = v;
    int g = batch[n];                     // wave-uniform
    if (g != gcur) {
      if (gcur >= 0) atomicAdd(&hcat[gcur * HC + layer * 128 + lane], accp);
      gcur = g; accp = 0.0f;
    }
    accp = fmaf(v, pmask[n], accp);
  }
  if (gcur >= 0) atomicAdd(&hcat[gcur * HC + layer * 128 + lane], accp);
}

// ---------------- center-node gather ----------------
__global__ __launch_bounds__(256) void center_kernel(
    const float* __restrict__ h, const int* __restrict__ mapping,
    float* __restrict__ hcat, int layer, int G)
{
  int gid = blockIdx.x * 256 + threadIdx.x;
  int g = gid >> 6, c = gid & 63;
  if (g >= G) return;
  hcat[g * HC + layer * 128 + 64 + c] = h[(size_t)mapping[g] * DD + c];
}

// ---------------- final linear: [G,384] @ [384,32] + b ----------------
__global__ __launch_bounds__(256) void final_kernel(
    const float* __restrict__ hcat, const float* __restrict__ lw,
    const float* __restrict__ lb, float* __restrict__ out, int G)
{
  int gid = blockIdx.x * 256 + threadIdx.x;
  int g = gid >> 5, s = gid & 31;
  if (g >= G) return;
  float acc = lb[s];
  for (int j = 0; j < HC; ++j)
    acc = fmaf(hcat[g * HC + j], lw[j * SS + s], acc);
  out[g * SS + s] = acc;
}

extern "C" void kernel_launch(void* const* d_in, const int* in_sizes, int n_in,
                              void* d_out, int out_size, void* d_ws, size_t ws_size,
                              hipStream_t stream)
{
  const float* x     = (const float*)d_in[0];
  const float* ew    = (const float*)d_in[1];
  const float* pmask = (const float*)d_in[2];
  const float* W1    = (const float*)d_in[3];
  const float* b1    = (const float*)d_in[4];
  const float* gma   = (const float*)d_in[5];
  const float* bta   = (const float*)d_in[6];
  const float* bnm   = (const float*)d_in[7];
  const float* bnv   = (const float*)d_in[8];
  const float* W2    = (const float*)d_in[9];
  const float* b2    = (const float*)d_in[10];
  const float* epsv  = (const float*)d_in[11];
  const float* lw    = (const float*)d_in[12];
  const float* lb    = (const float*)d_in[13];
  const int*   ei    = (const int*)d_in[14];
  const int*   batch = (const int*)d_in[15];
  const int*   mapping = (const int*)d_in[16];

  const int N = in_sizes[2];    // pooling_mask length
  const int E = in_sizes[1];    // edge_weight length
  const int G = in_sizes[16];   // mapping length

  float* bufA = (float*)d_ws;
  float* bufB = bufA + (size_t)N * DD;
  float* hcat = bufB + (size_t)N * DD;
  float* fout = (float*)d_out;

  hipMemsetAsync(hcat, 0, (size_t)G * HC * sizeof(float), stream);

  const float* hsrc = x;
  float* aggbuf = bufA;
  for (int layer = 0; layer < 3; ++layer) {
    hipMemsetAsync(aggbuf, 0, (size_t)N * DD * sizeof(float), stream);
    int agrid = (E * 16 + 255) / 256;
    agg_kernel<<<agrid, 256, 0, stream>>>(hsrc, ew, ei, aggbuf, E);
    int ngrid = (N + 255) / 256;
    node_kernel<<<ngrid, 256, 0, stream>>>(hsrc, aggbuf, W1, b1, gma, bta,
        bnm, bnv, W2, b2, epsv, pmask, batch, aggbuf, hcat, layer, N);
    center_kernel<<<(G * DD + 255) / 256, 256, 0, stream>>>(
        aggbuf, mapping, hcat, layer, G);
    hsrc = aggbuf;
    aggbuf = (layer == 0) ? bufB : ((layer == 1) ? bufA : bufB);
  }
  final_kernel<<<(G * SS + 255) / 256, 256, 0, stream>>>(hcat, lw, lb, fout, G);
}

// Round 2
// 758.714 us; speedup vs baseline: 3.1699x; 3.1699x over previous
//
#include <hip/hip_runtime.h>

#define DD 64
#define HC 384   // 2*D*L = hcat columns
#define SS 32

// ---------------- CSR build ----------------
__global__ __launch_bounds__(256) void hist_kernel(
    const int* __restrict__ ei, int* __restrict__ cnt, int E)
{
  int e = blockIdx.x * 256 + threadIdx.x;
  if (e >= E) return;
  atomicAdd(&cnt[ei[E + e]], 1);   // dst
}

__global__ __launch_bounds__(256) void scan_kernel(int* cnt, int total)
{
  __shared__ int sums[256];
  int t = threadIdx.x;
  int strip = (total + 255) / 256;
  int beg = t * strip, end = min(beg + strip, total);
  int s = 0;
  for (int i = beg; i < end; ++i) s += cnt[i];
  sums[t] = s;
  __syncthreads();
  if (t == 0) {
    int c = 0;
    for (int i = 0; i < 256; ++i) { int v = sums[i]; sums[i] = c; c += v; }
  }
  __syncthreads();
  int c = sums[t];
  for (int i = beg; i < end; ++i) { int v = cnt[i]; cnt[i] = c; c += v; }
}

__global__ __launch_bounds__(256) void scatter_kernel(
    const int* __restrict__ ei, const float* __restrict__ ew,
    int* __restrict__ cur, int2* __restrict__ packed, int E)
{
  int e = blockIdx.x * 256 + threadIdx.x;
  if (e >= E) return;
  int d = ei[E + e];
  int pos = atomicAdd(&cur[d], 1);
  packed[pos] = make_int2(ei[e], __float_as_int(ew[e]));
}

// ---------------- gather + z: wave per node, lane = channel ----------------
__global__ __launch_bounds__(256) void gather_kernel(
    const float* __restrict__ h, const int2* __restrict__ packed,
    const int* __restrict__ off, const float* __restrict__ epsv,
    float* __restrict__ z, int layer, int N)
{
  int wave = threadIdx.x >> 6;
  int lane = threadIdx.x & 63;
  int n = blockIdx.x * 4 + wave;
  if (n >= N) return;
  int beg = off[n], end = off[n + 1];   // wave-uniform broadcast
  float acc = 0.0f;
  for (int e = beg; e < end; ++e) {
    int2 p = packed[e];                 // broadcast 8B
    acc = fmaf(__int_as_float(p.y), h[(size_t)p.x * DD + lane], acc);
  }
  size_t idx = (size_t)n * DD + lane;
  z[idx] = fmaf(1.0f + epsv[layer], h[idx], acc);
}

// ---------------- per-node GIN MLP + masked add-pool (in-place on z) ----------------
__global__ __launch_bounds__(256) void node_kernel(
    float* __restrict__ z,
    const float* __restrict__ W1, const float* __restrict__ b1,
    const float* __restrict__ gamma, const float* __restrict__ beta,
    const float* __restrict__ bnm, const float* __restrict__ bnv,
    const float* __restrict__ W2, const float* __restrict__ b2,
    const float* __restrict__ pmask, const int* __restrict__ batch,
    float* __restrict__ hcat, int layer, int N)
{
  __shared__ float tile_s[4][DD * DD];   // 64 KB
  const int wave = threadIdx.x >> 6;
  const int lane = threadIdx.x & 63;
  float* tile = tile_s[wave];
  const int n0 = blockIdx.x * 256 + wave * 64;
  const float* W1l = W1 + layer * DD * DD;
  const float* W2l = W2 + layer * DD * DD;

  // phase 1: stage z tile (coalesced; lane = channel), XOR-swizzled LDS
  for (int r = 0; r < 64; ++r) {
    int n = n0 + r;
    float v = (n < N) ? z[(size_t)n * DD + lane] : 0.0f;
    tile[r * DD + ((lane + r) & 63)] = v;
  }
  __syncthreads();

  // phase 2: lane = node. GEMM1
  float t[DD];
  #pragma unroll
  for (int c = 0; c < DD; ++c) t[c] = 0.0f;
  for (int k = 0; k < DD; ++k) {
    float zk = tile[lane * DD + ((k + lane) & 63)];
    #pragma unroll
    for (int c = 0; c < DD; ++c)
      t[c] = fmaf(zk, W1l[k * DD + c], t[c]);
  }
  #pragma unroll
  for (int c = 0; c < DD; ++c) {
    float A = gamma[layer * DD + c] * rsqrtf(bnv[layer * DD + c] + 1e-5f);
    float B = fmaf(b1[layer * DD + c] - bnm[layer * DD + c], A,
                   beta[layer * DD + c]);
    tile[lane * DD + ((c + lane) & 63)] = fmaxf(fmaf(t[c], A, B), 0.0f);
  }
  // GEMM2
  #pragma unroll
  for (int c = 0; c < DD; ++c) t[c] = 0.0f;
  for (int k = 0; k < DD; ++k) {
    float zk = tile[lane * DD + ((k + lane) & 63)];
    #pragma unroll
    for (int c = 0; c < DD; ++c)
      t[c] = fmaf(zk, W2l[k * DD + c], t[c]);
  }
  #pragma unroll
  for (int c = 0; c < DD; ++c)
    tile[lane * DD + ((c + lane) & 63)] =
        fmaxf(t[c] + b2[layer * DD + c], 0.0f);
  __syncthreads();

  // phase 3: coalesced store in place + run-length pooled atomicAdd
  float accp = 0.0f;
  int gcur = -1;
  for (int r = 0; r < 64; ++r) {
    int n = n0 + r;
    if (n >= N) break;
    float v = tile[r * DD + ((lane + r) & 63)];
    z[(size_t)n * DD + lane] = v;
    int g = batch[n];
    if (g != gcur) {
      if (gcur >= 0) atomicAdd(&hcat[gcur * HC + layer * 128 + lane], accp);
      gcur = g; accp = 0.0f;
    }
    accp = fmaf(v, pmask[n], accp);
  }
  if (gcur >= 0) atomicAdd(&hcat[gcur * HC + layer * 128 + lane], accp);
}

// ---------------- center-node gather ----------------
__global__ __launch_bounds__(256) void center_kernel(
    const float* __restrict__ h, const int* __restrict__ mapping,
    float* __restrict__ hcat, int layer, int G)
{
  int gid = blockIdx.x * 256 + threadIdx.x;
  int g = gid >> 6, c = gid & 63;
  if (g >= G) return;
  hcat[g * HC + layer * 128 + 64 + c] = h[(size_t)mapping[g] * DD + c];
}

// ---------------- final linear: [G,384] @ [384,32] + b ----------------
__global__ __launch_bounds__(256) void final_kernel(
    const float* __restrict__ hcat, const float* __restrict__ lw,
    const float* __restrict__ lb, float* __restrict__ out, int G)
{
  int gid = blockIdx.x * 256 + threadIdx.x;
  int g = gid >> 5, s = gid & 31;
  if (g >= G) return;
  float acc = lb[s];
  for (int j = 0; j < HC; ++j)
    acc = fmaf(hcat[g * HC + j], lw[j * SS + s], acc);
  out[g * SS + s] = acc;
}

extern "C" void kernel_launch(void* const* d_in, const int* in_sizes, int n_in,
                              void* d_out, int out_size, void* d_ws, size_t ws_size,
                              hipStream_t stream)
{
  const float* x     = (const float*)d_in[0];
  const float* ew    = (const float*)d_in[1];
  const float* pmask = (const float*)d_in[2];
  const float* W1    = (const float*)d_in[3];
  const float* b1    = (const float*)d_in[4];
  const float* gma   = (const float*)d_in[5];
  const float* bta   = (const float*)d_in[6];
  const float* bnm   = (const float*)d_in[7];
  const float* bnv   = (const float*)d_in[8];
  const float* W2    = (const float*)d_in[9];
  const float* b2    = (const float*)d_in[10];
  const float* epsv  = (const float*)d_in[11];
  const float* lw    = (const float*)d_in[12];
  const float* lb    = (const float*)d_in[13];
  const int*   ei    = (const int*)d_in[14];
  const int*   batch = (const int*)d_in[15];
  const int*   mapping = (const int*)d_in[16];

  const int N = in_sizes[2];    // pooling_mask length
  const int E = in_sizes[1];    // edge_weight length
  const int G = in_sizes[16];   // mapping length

  float* bufA = (float*)d_ws;                       // N*DD
  float* bufB = bufA + (size_t)N * DD;              // N*DD
  float* hcat = bufB + (size_t)N * DD;              // G*HC
  int*   off  = (int*)(hcat + (size_t)G * HC);      // N+1
  int*   cur  = off + (N + 1);                      // N+1
  int2*  packed = (int2*)(cur + (N + 1));           // E
  float* fout = (float*)d_out;

  // ---- CSR build (edge_index constant across layers) ----
  hipMemsetAsync(off, 0, (N + 1) * sizeof(int), stream);
  int egrid = (E + 255) / 256;
  hist_kernel<<<egrid, 256, 0, stream>>>(ei, off, E);
  scan_kernel<<<1, 256, 0, stream>>>(off, N + 1);
  hipMemcpyAsync(cur, off, (N + 1) * sizeof(int),
                 hipMemcpyDeviceToDevice, stream);
  scatter_kernel<<<egrid, 256, 0, stream>>>(ei, ew, cur, packed, E);

  hipMemsetAsync(hcat, 0, (size_t)G * HC * sizeof(float), stream);

  // ---- 3 GIN layers ----
  const float* hsrc = x;
  float* zbuf = bufA;
  for (int layer = 0; layer < 3; ++layer) {
    gather_kernel<<<(N + 3) / 4, 256, 0, stream>>>(
        hsrc, packed, off, epsv, zbuf, layer, N);
    node_kernel<<<(N + 255) / 256, 256, 0, stream>>>(
        zbuf, W1, b1, gma, bta, bnm, bnv, W2, b2,
        pmask, batch, hcat, layer, N);
    center_kernel<<<(G * DD + 255) / 256, 256, 0, stream>>>(
        zbuf, mapping, hcat, layer, G);
    hsrc = zbuf;
    zbuf = (zbuf == bufA) ? bufB : bufA;
  }
  final_kernel<<<(G * SS + 255) / 256, 256, 0, stream>>>(hcat, lw, lb, fout, G);
}

// Round 3
// 544.460 us; speedup vs baseline: 4.4173x; 1.3935x over previous
//
#include <hip/hip_runtime.h>

#define DD 64
#define HC 384   // 2*D*L
#define SS 32

// ---------------- CSR build ----------------
__global__ __launch_bounds__(256) void hist_kernel(
    const int* __restrict__ ei, int* __restrict__ cnt, int E)
{
  int e = blockIdx.x * 256 + threadIdx.x;
  if (e >= E) return;
  atomicAdd(&cnt[ei[E + e]], 1);
}

// 3-pass exclusive scan over n ints (n <= 256*1024)
__global__ __launch_bounds__(256) void scan1_kernel(
    const int* __restrict__ cnt, int* __restrict__ out,
    int* __restrict__ bsum, int n)
{
  int t = threadIdx.x;
  int base = blockIdx.x * 1024 + t * 4;
  int c0 = (base + 0 < n) ? cnt[base + 0] : 0;
  int c1 = (base + 1 < n) ? cnt[base + 1] : 0;
  int c2 = (base + 2 < n) ? cnt[base + 2] : 0;
  int c3 = (base + 3 < n) ? cnt[base + 3] : 0;
  int s = c0 + c1 + c2 + c3;
  __shared__ int sc[256];
  sc[t] = s;
  __syncthreads();
  for (int o = 1; o < 256; o <<= 1) {
    int v = (t >= o) ? sc[t - o] : 0;
    __syncthreads();
    sc[t] += v;
    __syncthreads();
  }
  int run = sc[t] - s;   // exclusive prefix of this thread within block
  if (t == 255) bsum[blockIdx.x] = sc[255];
  if (base + 0 < n) out[base + 0] = run; run += c0;
  if (base + 1 < n) out[base + 1] = run; run += c1;
  if (base + 2 < n) out[base + 2] = run; run += c2;
  if (base + 3 < n) out[base + 3] = run;
}

__global__ void scan2_kernel(int* bsum, int nb)
{
  if (threadIdx.x == 0) {
    int c = 0;
    for (int i = 0; i < nb; ++i) { int v = bsum[i]; bsum[i] = c; c += v; }
  }
}

__global__ __launch_bounds__(256) void scan3_kernel(
    int* __restrict__ out, const int* __restrict__ bsum, int n)
{
  int base = blockIdx.x * 1024 + threadIdx.x * 4;
  int add = bsum[blockIdx.x];
  #pragma unroll
  for (int j = 0; j < 4; ++j)
    if (base + j < n) out[base + j] += add;
}

__global__ __launch_bounds__(256) void scatter_kernel(
    const int* __restrict__ ei, const float* __restrict__ ew,
    int* __restrict__ cur, int2* __restrict__ packed, int E)
{
  int e = blockIdx.x * 256 + threadIdx.x;
  if (e >= E) return;
  int d = ei[E + e];
  int pos = atomicAdd(&cur[d], 1);
  packed[pos] = make_int2(ei[e], __float_as_int(ew[e]));
}

// ---------------- gather + z: wave per node, lane = channel, 4x unroll ----------------
__global__ __launch_bounds__(256) void gather_kernel(
    const float* __restrict__ h, const int2* __restrict__ packed,
    const int* __restrict__ off, const float* __restrict__ epsv,
    float* __restrict__ z, int layer, int N)
{
  int wave = threadIdx.x >> 6;
  int lane = threadIdx.x & 63;
  int n = blockIdx.x * 4 + wave;
  if (n >= N) return;
  int beg = off[n], end = off[n + 1];
  float acc = 0.0f;
  int e = beg;
  for (; e + 4 <= end; e += 4) {
    int2 p0 = packed[e + 0];
    int2 p1 = packed[e + 1];
    int2 p2 = packed[e + 2];
    int2 p3 = packed[e + 3];
    float h0 = h[(size_t)p0.x * DD + lane];
    float h1 = h[(size_t)p1.x * DD + lane];
    float h2 = h[(size_t)p2.x * DD + lane];
    float h3 = h[(size_t)p3.x * DD + lane];
    acc = fmaf(__int_as_float(p0.y), h0, acc);
    acc = fmaf(__int_as_float(p1.y), h1, acc);
    acc = fmaf(__int_as_float(p2.y), h2, acc);
    acc = fmaf(__int_as_float(p3.y), h3, acc);
  }
  for (; e < end; ++e) {
    int2 p = packed[e];
    acc = fmaf(__int_as_float(p.y), h[(size_t)p.x * DD + lane], acc);
  }
  size_t idx = (size_t)n * DD + lane;
  z[idx] = fmaf(1.0f + epsv[layer], h[idx], acc);
}

// ---------------- per-node GIN MLP + pooling ----------------
// Block = 256 (4 waves) handles 64 nodes. Waves split the 64 output
// channels (16 each). XOR-swizzled LDS tiles -> 2-way bank alias (free).
__global__ __launch_bounds__(256) void node_kernel(
    float* __restrict__ z,
    const float* __restrict__ W1, const float* __restrict__ b1,
    const float* __restrict__ gamma, const float* __restrict__ beta,
    const float* __restrict__ bnm, const float* __restrict__ bnv,
    const float* __restrict__ W2, const float* __restrict__ b2,
    const float* __restrict__ pmask, const int* __restrict__ batch,
    float* __restrict__ hcat, int layer, int N)
{
  __shared__ float tileZ[DD * DD];   // 16 KB
  __shared__ float tileT[DD * DD];   // 16 KB
  const int wave = threadIdx.x >> 6;
  const int lane = threadIdx.x & 63;
  const int n0 = blockIdx.x * 64;
  const int c0 = wave * 16;
  const float* W1l = W1 + layer * DD * DD;
  const float* W2l = W2 + layer * DD * DD;

  // phase 1: stage z rows (wave w -> rows w*16..w*16+15), lane = channel
  for (int i = 0; i < 16; ++i) {
    int r = wave * 16 + i;
    int n = n0 + r;
    float v = (n < N) ? z[(size_t)n * DD + lane] : 0.0f;
    tileZ[r * DD + ((lane + r) & 63)] = v;
  }
  __syncthreads();

  // phase 2: GEMM1, lane = node, this wave computes channels c0..c0+15
  float t[16];
  #pragma unroll
  for (int cc = 0; cc < 16; ++cc) t[cc] = 0.0f;
  for (int k = 0; k < DD; ++k) {
    float zk = tileZ[lane * DD + ((k + lane) & 63)];
    #pragma unroll
    for (int cc = 0; cc < 16; ++cc)
      t[cc] = fmaf(zk, W1l[k * DD + c0 + cc], t[cc]);
  }
  #pragma unroll
  for (int cc = 0; cc < 16; ++cc) {
    int c = c0 + cc;
    float A = gamma[layer * DD + c] * rsqrtf(bnv[layer * DD + c] + 1e-5f);
    float B = fmaf(b1[layer * DD + c] - bnm[layer * DD + c], A,
                   beta[layer * DD + c]);
    tileT[lane * DD + ((c + lane) & 63)] = fmaxf(fmaf(t[cc], A, B), 0.0f);
  }
  __syncthreads();

  // phase 3: GEMM2 (reads tileT, writes h_new into tileZ)
  #pragma unroll
  for (int cc = 0; cc < 16; ++cc) t[cc] = 0.0f;
  for (int k = 0; k < DD; ++k) {
    float zk = tileT[lane * DD + ((k + lane) & 63)];
    #pragma unroll
    for (int cc = 0; cc < 16; ++cc)
      t[cc] = fmaf(zk, W2l[k * DD + c0 + cc], t[cc]);
  }
  #pragma unroll
  for (int cc = 0; cc < 16; ++cc) {
    int c = c0 + cc;
    tileZ[lane * DD + ((c + lane) & 63)] =
        fmaxf(t[cc] + b2[layer * DD + c], 0.0f);
  }
  __syncthreads();

  // phase 4: coalesced store in place + run-length pooled atomicAdd
  float accp = 0.0f;
  int gcur = -1;
  for (int i = 0; i < 16; ++i) {
    int r = wave * 16 + i;
    int n = n0 + r;
    if (n >= N) break;
    float v = tileZ[r * DD + ((lane + r) & 63)];
    z[(size_t)n * DD + lane] = v;
    int g = batch[n];
    if (g != gcur) {
      if (gcur >= 0) atomicAdd(&hcat[gcur * HC + layer * 128 + lane], accp);
      gcur = g; accp = 0.0f;
    }
    accp = fmaf(v, pmask[n], accp);
  }
  if (gcur >= 0) atomicAdd(&hcat[gcur * HC + layer * 128 + lane], accp);
}

// ---------------- center-node gather ----------------
__global__ __launch_bounds__(256) void center_kernel(
    const float* __restrict__ h, const int* __restrict__ mapping,
    float* __restrict__ hcat, int layer, int G)
{
  int gid = blockIdx.x * 256 + threadIdx.x;
  int g = gid >> 6, c = gid & 63;
  if (g >= G) return;
  hcat[g * HC + layer * 128 + 64 + c] = h[(size_t)mapping[g] * DD + c];
}

// ---------------- final linear: [G,384] @ [384,32] + b ----------------
__global__ __launch_bounds__(256) void final_kernel(
    const float* __restrict__ hcat, const float* __restrict__ lw,
    const float* __restrict__ lb, float* __restrict__ out, int G)
{
  int gid = blockIdx.x * 256 + threadIdx.x;
  int g = gid >> 5, s = gid & 31;
  if (g >= G) return;
  float acc = lb[s];
  for (int j = 0; j < HC; ++j)
    acc = fmaf(hcat[g * HC + j], lw[j * SS + s], acc);
  out[g * SS + s] = acc;
}

extern "C" void kernel_launch(void* const* d_in, const int* in_sizes, int n_in,
                              void* d_out, int out_size, void* d_ws, size_t ws_size,
                              hipStream_t stream)
{
  const float* x     = (const float*)d_in[0];
  const float* ew    = (const float*)d_in[1];
  const float* pmask = (const float*)d_in[2];
  const float* W1    = (const float*)d_in[3];
  const float* b1    = (const float*)d_in[4];
  const float* gma   = (const float*)d_in[5];
  const float* bta   = (const float*)d_in[6];
  const float* bnm   = (const float*)d_in[7];
  const float* bnv   = (const float*)d_in[8];
  const float* W2    = (const float*)d_in[9];
  const float* b2    = (const float*)d_in[10];
  const float* epsv  = (const float*)d_in[11];
  const float* lw    = (const float*)d_in[12];
  const float* lb    = (const float*)d_in[13];
  const int*   ei    = (const int*)d_in[14];
  const int*   batch = (const int*)d_in[15];
  const int*   mapping = (const int*)d_in[16];

  const int N = in_sizes[2];
  const int E = in_sizes[1];
  const int G = in_sizes[16];

  float* bufA = (float*)d_ws;                       // N*DD
  float* bufB = bufA + (size_t)N * DD;              // N*DD
  float* hcat = bufB + (size_t)N * DD;              // G*HC
  int*   cnt  = (int*)(hcat + (size_t)G * HC);      // N+1
  int*   off  = cnt + (N + 1);                      // N+1
  int*   cur  = off + (N + 1);                      // N+1
  int*   bsum = cur + (N + 1);                      // 256
  int2*  packed = (int2*)(bsum + 256);              // E
  float* fout = (float*)d_out;

  const int n1 = N + 1;
  const int nscan_blocks = (n1 + 1023) / 1024;

  // ---- CSR build ----
  hipMemsetAsync(cnt, 0, n1 * sizeof(int), stream);
  int egrid = (E + 255) / 256;
  hist_kernel<<<egrid, 256, 0, stream>>>(ei, cnt, E);
  scan1_kernel<<<nscan_blocks, 256, 0, stream>>>(cnt, off, bsum, n1);
  scan2_kernel<<<1, 64, 0, stream>>>(bsum, nscan_blocks);
  scan3_kernel<<<nscan_blocks, 256, 0, stream>>>(off, bsum, n1);
  hipMemcpyAsync(cur, off, n1 * sizeof(int), hipMemcpyDeviceToDevice, stream);
  scatter_kernel<<<egrid, 256, 0, stream>>>(ei, ew, cur, packed, E);

  hipMemsetAsync(hcat, 0, (size_t)G * HC * sizeof(float), stream);

  // ---- 3 GIN layers ----
  const float* hsrc = x;
  float* zbuf = bufA;
  for (int layer = 0; layer < 3; ++layer) {
    gather_kernel<<<(N + 3) / 4, 256, 0, stream>>>(
        hsrc, packed, off, epsv, zbuf, layer, N);
    node_kernel<<<(N + 63) / 64, 256, 0, stream>>>(
        zbuf, W1, b1, gma, bta, bnm, bnv, W2, b2,
        pmask, batch, hcat, layer, N);
    center_kernel<<<(G * DD + 255) / 256, 256, 0, stream>>>(
        zbuf, mapping, hcat, layer, G);
    hsrc = zbuf;
    zbuf = (zbuf == bufA) ? bufB : bufA;
  }
  final_kernel<<<(G * SS + 255) / 256, 256, 0, stream>>>(hcat, lw, lb, fout, G);
}

// Round 4
// 407.300 us; speedup vs baseline: 5.9048x; 1.3368x over previous
//
#include <hip/hip_runtime.h>

#define DD 64
#define HC 384   // 2*D*L
#define SS 32

// ---------------- CSR build ----------------
__global__ __launch_bounds__(256) void hist_kernel(
    const int* __restrict__ ei, int* __restrict__ cnt, int E)
{
  int e = blockIdx.x * 256 + threadIdx.x;
  if (e >= E) return;
  atomicAdd(&cnt[ei[E + e]], 1);
}

__global__ __launch_bounds__(256) void scan1_kernel(
    const int* __restrict__ cnt, int* __restrict__ out,
    int* __restrict__ bsum, int n)
{
  int t = threadIdx.x;
  int base = blockIdx.x * 1024 + t * 4;
  int c0 = (base + 0 < n) ? cnt[base + 0] : 0;
  int c1 = (base + 1 < n) ? cnt[base + 1] : 0;
  int c2 = (base + 2 < n) ? cnt[base + 2] : 0;
  int c3 = (base + 3 < n) ? cnt[base + 3] : 0;
  int s = c0 + c1 + c2 + c3;
  __shared__ int sc[256];
  sc[t] = s;
  __syncthreads();
  for (int o = 1; o < 256; o <<= 1) {
    int v = (t >= o) ? sc[t - o] : 0;
    __syncthreads();
    sc[t] += v;
    __syncthreads();
  }
  int run = sc[t] - s;
  if (t == 255) bsum[blockIdx.x] = sc[255];
  if (base + 0 < n) out[base + 0] = run; run += c0;
  if (base + 1 < n) out[base + 1] = run; run += c1;
  if (base + 2 < n) out[base + 2] = run; run += c2;
  if (base + 3 < n) out[base + 3] = run;
}

// parallel exclusive scan of block sums (nb <= 256), one block
__global__ __launch_bounds__(256) void scan2_kernel(int* bsum, int nb)
{
  __shared__ int s[256];
  int t = threadIdx.x;
  int v = (t < nb) ? bsum[t] : 0;
  s[t] = v;
  __syncthreads();
  for (int o = 1; o < 256; o <<= 1) {
    int u = (t >= o) ? s[t - o] : 0;
    __syncthreads();
    s[t] += u;
    __syncthreads();
  }
  if (t < nb) bsum[t] = s[t] - v;   // exclusive
}

__global__ __launch_bounds__(256) void scan3_kernel(
    int* __restrict__ out, const int* __restrict__ bsum, int n)
{
  int base = blockIdx.x * 1024 + threadIdx.x * 4;
  int add = bsum[blockIdx.x];
  #pragma unroll
  for (int j = 0; j < 4; ++j)
    if (base + j < n) out[base + j] += add;
}

__global__ __launch_bounds__(256) void scatter_kernel(
    const int* __restrict__ ei, const float* __restrict__ ew,
    int* __restrict__ cur, int2* __restrict__ packed, int E)
{
  int e = blockIdx.x * 256 + threadIdx.x;
  if (e >= E) return;
  int d = ei[E + e];
  int pos = atomicAdd(&cur[d], 1);
  packed[pos] = make_int2(ei[e], __float_as_int(ew[e]));
}

// ---------------- gather + z ----------------
// wave per node; 4 edge-subgroups x 16 lanes; lane handles a float4 channel
// quad. 16 outstanding row loads per wave; shfl_xor cross-subgroup reduce.
__global__ __launch_bounds__(256) void gather_kernel(
    const float* __restrict__ h, const int2* __restrict__ packed,
    const int* __restrict__ off, const float* __restrict__ epsv,
    float* __restrict__ z, int layer, int N)
{
  int wave = threadIdx.x >> 6;
  int lane = threadIdx.x & 63;
  int sub = lane >> 4;        // edge subgroup 0..3
  int lq = (lane & 15) * 4;   // channel quad
  int n = blockIdx.x * 4 + wave;
  if (n >= N) return;
  int beg = off[n], end = off[n + 1];
  float ax = 0.f, ay = 0.f, az = 0.f, aw = 0.f;
  int e = beg + sub;
  for (; e + 12 < end; e += 16) {
    int2 p0 = packed[e];
    int2 p1 = packed[e + 4];
    int2 p2 = packed[e + 8];
    int2 p3 = packed[e + 12];
    float4 h0 = *(const float4*)(h + (size_t)p0.x * DD + lq);
    float4 h1 = *(const float4*)(h + (size_t)p1.x * DD + lq);
    float4 h2 = *(const float4*)(h + (size_t)p2.x * DD + lq);
    float4 h3 = *(const float4*)(h + (size_t)p3.x * DD + lq);
    float w0 = __int_as_float(p0.y), w1 = __int_as_float(p1.y);
    float w2 = __int_as_float(p2.y), w3 = __int_as_float(p3.y);
    ax = fmaf(w0, h0.x, ax); ay = fmaf(w0, h0.y, ay);
    az = fmaf(w0, h0.z, az); aw = fmaf(w0, h0.w, aw);
    ax = fmaf(w1, h1.x, ax); ay = fmaf(w1, h1.y, ay);
    az = fmaf(w1, h1.z, az); aw = fmaf(w1, h1.w, aw);
    ax = fmaf(w2, h2.x, ax); ay = fmaf(w2, h2.y, ay);
    az = fmaf(w2, h2.z, az); aw = fmaf(w2, h2.w, aw);
    ax = fmaf(w3, h3.x, ax); ay = fmaf(w3, h3.y, ay);
    az = fmaf(w3, h3.z, az); aw = fmaf(w3, h3.w, aw);
  }
  for (; e < end; e += 4) {
    int2 p = packed[e];
    float4 hv = *(const float4*)(h + (size_t)p.x * DD + lq);
    float w = __int_as_float(p.y);
    ax = fmaf(w, hv.x, ax); ay = fmaf(w, hv.y, ay);
    az = fmaf(w, hv.z, az); aw = fmaf(w, hv.w, aw);
  }
  // reduce across subgroups (lanes differ in bits 4,5)
  ax += __shfl_xor(ax, 16); ay += __shfl_xor(ay, 16);
  az += __shfl_xor(az, 16); aw += __shfl_xor(aw, 16);
  ax += __shfl_xor(ax, 32); ay += __shfl_xor(ay, 32);
  az += __shfl_xor(az, 32); aw += __shfl_xor(aw, 32);
  if (sub == 0) {
    float e1 = 1.0f + epsv[layer];
    const float4 hv = *(const float4*)(h + (size_t)n * DD + lq);
    float4 o;
    o.x = fmaf(e1, hv.x, ax); o.y = fmaf(e1, hv.y, ay);
    o.z = fmaf(e1, hv.z, az); o.w = fmaf(e1, hv.w, aw);
    *(float4*)(z + (size_t)n * DD + lq) = o;
  }
}

// ---------------- per-node GIN MLP + pooling ----------------
// Block = 256 (4 waves) handles 64 nodes; waves split 64 output channels
// (16 each). c0 forced into SGPR via readfirstlane so ALL weight/BN loads
// are scalar (s_load) -> k-loop body is 1 ds_read + 16 v_fmac.
__global__ __launch_bounds__(256) void node_kernel(
    float* __restrict__ z,
    const float* __restrict__ W1, const float* __restrict__ b1,
    const float* __restrict__ gamma, const float* __restrict__ beta,
    const float* __restrict__ bnm, const float* __restrict__ bnv,
    const float* __restrict__ W2, const float* __restrict__ b2,
    const float* __restrict__ pmask, const int* __restrict__ batch,
    float* __restrict__ hcat, int layer, int N)
{
  __shared__ float tileZ[DD * DD];   // 16 KB
  __shared__ float tileT[DD * DD];   // 16 KB
  const int wave = threadIdx.x >> 6;
  const int lane = threadIdx.x & 63;
  const int n0 = blockIdx.x * 64;
  const int c0 = __builtin_amdgcn_readfirstlane(wave * 16);  // SGPR!
  const float* W1l = W1 + layer * DD * DD;
  const float* W2l = W2 + layer * DD * DD;

  // phase 1: stage z rows, lane = channel
  #pragma unroll
  for (int i = 0; i < 16; ++i) {
    int r = c0 + i;                      // this wave's 16 rows
    int n = n0 + r;
    float v = (n < N) ? z[(size_t)n * DD + lane] : 0.0f;
    tileZ[r * DD + ((lane + r) & 63)] = v;
  }
  __syncthreads();

  // phase 2: GEMM1, lane = node, channels c0..c0+15
  float t[16];
  #pragma unroll
  for (int cc = 0; cc < 16; ++cc) t[cc] = 0.0f;
  #pragma unroll 2
  for (int k = 0; k < DD; ++k) {
    float zk = tileZ[lane * DD + ((k + lane) & 63)];
    #pragma unroll
    for (int cc = 0; cc < 16; ++cc)
      t[cc] = fmaf(zk, W1l[k * DD + c0 + cc], t[cc]);   // scalar W
  }
  #pragma unroll
  for (int cc = 0; cc < 16; ++cc) {
    int c = c0 + cc;
    float A = gamma[layer * DD + c] * rsqrtf(bnv[layer * DD + c] + 1e-5f);
    float B = fmaf(b1[layer * DD + c] - bnm[layer * DD + c], A,
                   beta[layer * DD + c]);
    tileT[lane * DD + ((c + lane) & 63)] = fmaxf(fmaf(t[cc], A, B), 0.0f);
  }
  __syncthreads();

  // phase 3: GEMM2
  #pragma unroll
  for (int cc = 0; cc < 16; ++cc) t[cc] = 0.0f;
  #pragma unroll 2
  for (int k = 0; k < DD; ++k) {
    float zk = tileT[lane * DD + ((k + lane) & 63)];
    #pragma unroll
    for (int cc = 0; cc < 16; ++cc)
      t[cc] = fmaf(zk, W2l[k * DD + c0 + cc], t[cc]);   // scalar W
  }
  #pragma unroll
  for (int cc = 0; cc < 16; ++cc) {
    int c = c0 + cc;
    tileZ[lane * DD + ((c + lane) & 63)] =
        fmaxf(t[cc] + b2[layer * DD + c], 0.0f);
  }
  __syncthreads();

  // phase 4: coalesced store in place + run-length pooled atomicAdd
  float accp = 0.0f;
  int gcur = -1;
  for (int i = 0; i < 16; ++i) {
    int r = c0 + i;
    int n = n0 + r;
    if (n >= N) break;
    float v = tileZ[r * DD + ((lane + r) & 63)];
    z[(size_t)n * DD + lane] = v;
    int g = batch[n];                    // uniform n -> s_load
    if (g != gcur) {
      if (gcur >= 0) atomicAdd(&hcat[gcur * HC + layer * 128 + lane], accp);
      gcur = g; accp = 0.0f;
    }
    accp = fmaf(v, pmask[n], accp);
  }
  if (gcur >= 0) atomicAdd(&hcat[gcur * HC + layer * 128 + lane], accp);
}

// ---------------- center-node gather (float4) ----------------
__global__ __launch_bounds__(256) void center_kernel(
    const float* __restrict__ h, const int* __restrict__ mapping,
    float* __restrict__ hcat, int layer, int G)
{
  int gid = blockIdx.x * 256 + threadIdx.x;
  int g = gid >> 4, q = (gid & 15) * 4;
  if (g >= G) return;
  float4 v = *(const float4*)(h + (size_t)mapping[g] * DD + q);
  *(float4*)(hcat + g * HC + layer * 128 + 64 + q) = v;
}

// ---------------- final linear: [G,384] @ [384,32] + b ----------------
__global__ __launch_bounds__(256) void final_kernel(
    const float* __restrict__ hcat, const float* __restrict__ lw,
    const float* __restrict__ lb, float* __restrict__ out, int G)
{
  int gid = blockIdx.x * 256 + threadIdx.x;
  int g = gid >> 5, s = gid & 31;
  if (g >= G) return;
  float acc = lb[s];
  #pragma unroll 4
  for (int j = 0; j < HC; ++j)
    acc = fmaf(hcat[g * HC + j], lw[j * SS + s], acc);
  out[g * SS + s] = acc;
}

extern "C" void kernel_launch(void* const* d_in, const int* in_sizes, int n_in,
                              void* d_out, int out_size, void* d_ws, size_t ws_size,
                              hipStream_t stream)
{
  const float* x     = (const float*)d_in[0];
  const float* ew    = (const float*)d_in[1];
  const float* pmask = (const float*)d_in[2];
  const float* W1    = (const float*)d_in[3];
  const float* b1    = (const float*)d_in[4];
  const float* gma   = (const float*)d_in[5];
  const float* bta   = (const float*)d_in[6];
  const float* bnm   = (const float*)d_in[7];
  const float* bnv   = (const float*)d_in[8];
  const float* W2    = (const float*)d_in[9];
  const float* b2    = (const float*)d_in[10];
  const float* epsv  = (const float*)d_in[11];
  const float* lw    = (const float*)d_in[12];
  const float* lb    = (const float*)d_in[13];
  const int*   ei    = (const int*)d_in[14];
  const int*   batch = (const int*)d_in[15];
  const int*   mapping = (const int*)d_in[16];

  const int N = in_sizes[2];
  const int E = in_sizes[1];
  const int G = in_sizes[16];

  float* bufA = (float*)d_ws;                       // N*DD
  float* bufB = bufA + (size_t)N * DD;              // N*DD
  float* hcat = bufB + (size_t)N * DD;              // G*HC
  int*   cnt  = (int*)(hcat + (size_t)G * HC);      // N+1
  int*   off  = cnt + (N + 1);                      // N+1
  int*   cur  = off + (N + 1);                      // N+1
  int*   bsum = cur + (N + 1);                      // 256
  int2*  packed = (int2*)(bsum + 256);              // E
  float* fout = (float*)d_out;

  const int n1 = N + 1;
  const int nscan_blocks = (n1 + 1023) / 1024;

  // ---- CSR build ----
  hipMemsetAsync(cnt, 0, n1 * sizeof(int), stream);
  int egrid = (E + 255) / 256;
  hist_kernel<<<egrid, 256, 0, stream>>>(ei, cnt, E);
  scan1_kernel<<<nscan_blocks, 256, 0, stream>>>(cnt, off, bsum, n1);
  scan2_kernel<<<1, 256, 0, stream>>>(bsum, nscan_blocks);
  scan3_kernel<<<nscan_blocks, 256, 0, stream>>>(off, bsum, n1);
  hipMemcpyAsync(cur, off, n1 * sizeof(int), hipMemcpyDeviceToDevice, stream);
  scatter_kernel<<<egrid, 256, 0, stream>>>(ei, ew, cur, packed, E);

  hipMemsetAsync(hcat, 0, (size_t)G * HC * sizeof(float), stream);

  // ---- 3 GIN layers ----
  const float* hsrc = x;
  float* zbuf = bufA;
  for (int layer = 0; layer < 3; ++layer) {
    gather_kernel<<<(N + 3) / 4, 256, 0, stream>>>(
        hsrc, packed, off, epsv, zbuf, layer, N);
    node_kernel<<<(N + 63) / 64, 256, 0, stream>>>(
        zbuf, W1, b1, gma, bta, bnm, bnv, W2, b2,
        pmask, batch, hcat, layer, N);
    center_kernel<<<(G * DD / 4 + 255) / 256, 256, 0, stream>>>(
        zbuf, mapping, hcat, layer, G);
    hsrc = zbuf;
    zbuf = (zbuf == bufA) ? bufB : bufA;
  }
  final_kernel<<<(G * SS + 255) / 256, 256, 0, stream>>>(hcat, lw, lb, fout, G);
}

// Round 5
// 360.695 us; speedup vs baseline: 6.6678x; 1.1292x over previous
//
#include <hip/hip_runtime.h>
#include <hip/hip_fp16.h>

#define DD 64
#define HC 384   // 2*D*L
#define SS 32
#define BINW 256    // nodes per bin (bin = dst >> 8)
#define CHUNK 4096  // edges per partition block

// ---------------- CSR build: locality-binned ----------------
__global__ __launch_bounds__(256) void bin_count_kernel(
    const int* __restrict__ ei, int* __restrict__ bin_cnt, int E)
{
  __shared__ int cnt[256];
  int t = threadIdx.x;
  cnt[t] = 0;
  __syncthreads();
  for (int e = blockIdx.x * 256 + t; e < E; e += gridDim.x * 256)
    atomicAdd(&cnt[ei[E + e] >> 8], 1);
  __syncthreads();
  if (cnt[t] > 0) atomicAdd(&bin_cnt[t], cnt[t]);
}

__global__ __launch_bounds__(256) void bin_scan_kernel(
    const int* __restrict__ bin_cnt, int* __restrict__ bin_base,
    int* __restrict__ bin_cur, int nbins)
{
  __shared__ int s[256];
  int t = threadIdx.x;
  int v = (t < nbins) ? bin_cnt[t] : 0;
  s[t] = v;
  __syncthreads();
  for (int o = 1; o < 256; o <<= 1) {
    int u = (t >= o) ? s[t - o] : 0;
    __syncthreads();
    s[t] += u;
    __syncthreads();
  }
  int excl = s[t] - v;
  if (t <= nbins) {
    bin_base[t] = excl;        // t == nbins gets total = E
    if (t < nbins) bin_cur[t] = excl;
  }
}

// partition edges into bins; LDS staging -> coalesced per-bin flush
__global__ __launch_bounds__(256) void bin_part_kernel(
    const int* __restrict__ ei, const float* __restrict__ ew,
    int* __restrict__ bin_cur, int* __restrict__ ebin_dst,
    int2* __restrict__ ebin_sw, int E)
{
  __shared__ int sdst[CHUNK];     // 16 KB
  __shared__ int2 ssw[CHUNK];     // 32 KB
  __shared__ int bcnt[256], boff[256], bcur[256], gbase[256], stmp[256];
  int t = threadIdx.x;
  int e0 = blockIdx.x * CHUNK;
  int m = min(CHUNK, E - e0);
  bcnt[t] = 0;
  __syncthreads();
  for (int i = t; i < m; i += 256)
    atomicAdd(&bcnt[ei[E + e0 + i] >> 8], 1);
  __syncthreads();
  int v = bcnt[t];
  stmp[t] = v;
  __syncthreads();
  for (int o = 1; o < 256; o <<= 1) {
    int u = (t >= o) ? stmp[t - o] : 0;
    __syncthreads();
    stmp[t] += u;
    __syncthreads();
  }
  boff[t] = stmp[t] - v;
  bcur[t] = stmp[t] - v;
  if (v > 0) gbase[t] = atomicAdd(&bin_cur[t], v);
  __syncthreads();
  for (int i = t; i < m; i += 256) {
    int d = ei[E + e0 + i];
    int b = d >> 8;
    int p = atomicAdd(&bcur[b], 1);
    sdst[p] = d;
    ssw[p] = make_int2(ei[e0 + i], __float_as_int(ew[e0 + i]));
  }
  __syncthreads();
  for (int i = t; i < m; i += 256) {
    int d = sdst[i];
    int b = d >> 8;
    int g = gbase[b] + (i - boff[b]);
    ebin_dst[g] = d;
    ebin_sw[g] = ssw[i];
  }
}

// one block per bin: local hist + scan -> off[], then scatter into the
// bin's own ~32 KB window of packed[] (L2-resident, no write amplification)
__global__ __launch_bounds__(256) void fine_csr_kernel(
    const int* __restrict__ ebin_dst, const int2* __restrict__ ebin_sw,
    const int* __restrict__ bin_base, int* __restrict__ off,
    int2* __restrict__ packed, int N, int E)
{
  __shared__ int cnt[256], loff[256], cur[256], stmp[256];
  int t = threadIdx.x;
  int b = blockIdx.x;
  int ebeg = bin_base[b], eend = bin_base[b + 1];
  int m = eend - ebeg;
  cnt[t] = 0;
  __syncthreads();
  for (int i = t; i < m; i += 256)
    atomicAdd(&cnt[ebin_dst[ebeg + i] & 255], 1);
  __syncthreads();
  int v = cnt[t];
  stmp[t] = v;
  __syncthreads();
  for (int o = 1; o < 256; o <<= 1) {
    int u = (t >= o) ? stmp[t - o] : 0;
    __syncthreads();
    stmp[t] += u;
    __syncthreads();
  }
  loff[t] = stmp[t] - v;
  cur[t] = loff[t];
  int node = b * BINW + t;
  if (node < N) off[node] = ebeg + loff[t];
  if (b == 0 && t == 0) off[N] = E;
  __syncthreads();
  for (int i = t; i < m; i += 256) {
    int d = ebin_dst[ebeg + i];
    int p = atomicAdd(&cur[d & 255], 1);
    packed[ebeg + p] = ebin_sw[ebeg + i];
  }
}

// ---------------- fp32 -> fp16 row cache ----------------
__global__ __launch_bounds__(256) void tohalf_kernel(
    const float* __restrict__ x, __half* __restrict__ hh, int total)
{
  int i = (blockIdx.x * 256 + threadIdx.x) * 8;
  if (i >= total) return;
  float4 a = *(const float4*)(x + i);
  float4 b = *(const float4*)(x + i + 4);
  __half2 o[4];
  o[0] = __floats2half2_rn(a.x, a.y);
  o[1] = __floats2half2_rn(a.z, a.w);
  o[2] = __floats2half2_rn(b.x, b.y);
  o[3] = __floats2half2_rn(b.z, b.w);
  *(float4*)(hh + i) = *(float4*)o;
}

// ---------------- gather + z (fp16 rows, fp32 accumulate) ----------------
// wave per node; 8 edge-subgroups x 8 lanes; lane holds 8 channels (16 B
// fp16 load). 16 edges in flight per wave; 3x shfl_xor reduce.
__global__ __launch_bounds__(256) void gather_kernel(
    const __half* __restrict__ hh, const float* __restrict__ h,
    const int2* __restrict__ packed, const int* __restrict__ off,
    const float* __restrict__ epsv, float* __restrict__ z, int layer, int N)
{
  int wave = threadIdx.x >> 6;
  int lane = threadIdx.x & 63;
  int sub = lane >> 3;          // 0..7
  int ch0 = (lane & 7) * 8;     // 8 channels per lane
  int n = blockIdx.x * 4 + wave;
  if (n >= N) return;
  int beg = off[n], end = off[n + 1];
  float acc[8] = {0, 0, 0, 0, 0, 0, 0, 0};
  int e = beg + sub;
  for (; e + 8 < end; e += 16) {
    int2 p0 = packed[e];
    int2 p1 = packed[e + 8];
    float4 r0 = *(const float4*)(hh + (size_t)p0.x * DD + ch0);
    float4 r1 = *(const float4*)(hh + (size_t)p1.x * DD + ch0);
    float w0 = __int_as_float(p0.y);
    float w1 = __int_as_float(p1.y);
    const __half2* H0 = (const __half2*)&r0;
    const __half2* H1 = (const __half2*)&r1;
    #pragma unroll
    for (int j = 0; j < 4; ++j) {
      float2 f0 = __half22float2(H0[j]);
      float2 f1 = __half22float2(H1[j]);
      acc[2 * j]     = fmaf(w0, f0.x, acc[2 * j]);
      acc[2 * j + 1] = fmaf(w0, f0.y, acc[2 * j + 1]);
      acc[2 * j]     = fmaf(w1, f1.x, acc[2 * j]);
      acc[2 * j + 1] = fmaf(w1, f1.y, acc[2 * j + 1]);
    }
  }
  for (; e < end; e += 8) {
    int2 p = packed[e];
    float4 r = *(const float4*)(hh + (size_t)p.x * DD + ch0);
    float w = __int_as_float(p.y);
    const __half2* H = (const __half2*)&r;
    #pragma unroll
    for (int j = 0; j < 4; ++j) {
      float2 f = __half22float2(H[j]);
      acc[2 * j]     = fmaf(w, f.x, acc[2 * j]);
      acc[2 * j + 1] = fmaf(w, f.y, acc[2 * j + 1]);
    }
  }
  #pragma unroll
  for (int j = 0; j < 8; ++j) {
    acc[j] += __shfl_xor(acc[j], 8);
    acc[j] += __shfl_xor(acc[j], 16);
    acc[j] += __shfl_xor(acc[j], 32);
  }
  if (sub == 0) {
    float e1 = 1.0f + epsv[layer];
    float4 s0 = *(const float4*)(h + (size_t)n * DD + ch0);
    float4 s1 = *(const float4*)(h + (size_t)n * DD + ch0 + 4);
    float4 o0, o1;
    o0.x = fmaf(e1, s0.x, acc[0]); o0.y = fmaf(e1, s0.y, acc[1]);
    o0.z = fmaf(e1, s0.z, acc[2]); o0.w = fmaf(e1, s0.w, acc[3]);
    o1.x = fmaf(e1, s1.x, acc[4]); o1.y = fmaf(e1, s1.y, acc[5]);
    o1.z = fmaf(e1, s1.z, acc[6]); o1.w = fmaf(e1, s1.w, acc[7]);
    *(float4*)(z + (size_t)n * DD + ch0) = o0;
    *(float4*)(z + (size_t)n * DD + ch0 + 4) = o1;
  }
}

// ---------------- per-node GIN MLP + pooling ----------------
__global__ __launch_bounds__(256) void node_kernel(
    float* __restrict__ z, __half* __restrict__ hhalf,
    const float* __restrict__ W1, const float* __restrict__ b1,
    const float* __restrict__ gamma, const float* __restrict__ beta,
    const float* __restrict__ bnm, const float* __restrict__ bnv,
    const float* __restrict__ W2, const float* __restrict__ b2,
    const float* __restrict__ pmask, const int* __restrict__ batch,
    float* __restrict__ hcat, int layer, int N, int write_half)
{
  __shared__ float tileZ[DD * DD];
  __shared__ float tileT[DD * DD];
  const int wave = threadIdx.x >> 6;
  const int lane = threadIdx.x & 63;
  const int n0 = blockIdx.x * 64;
  const int c0 = __builtin_amdgcn_readfirstlane(wave * 16);  // SGPR
  const float* W1l = W1 + layer * DD * DD;
  const float* W2l = W2 + layer * DD * DD;

  #pragma unroll
  for (int i = 0; i < 16; ++i) {
    int r = c0 + i;
    int n = n0 + r;
    float v = (n < N) ? z[(size_t)n * DD + lane] : 0.0f;
    tileZ[r * DD + ((lane + r) & 63)] = v;
  }
  __syncthreads();

  float t[16];
  #pragma unroll
  for (int cc = 0; cc < 16; ++cc) t[cc] = 0.0f;
  #pragma unroll 2
  for (int k = 0; k < DD; ++k) {
    float zk = tileZ[lane * DD + ((k + lane) & 63)];
    #pragma unroll
    for (int cc = 0; cc < 16; ++cc)
      t[cc] = fmaf(zk, W1l[k * DD + c0 + cc], t[cc]);   // scalar W
  }
  #pragma unroll
  for (int cc = 0; cc < 16; ++cc) {
    int c = c0 + cc;
    float A = gamma[layer * DD + c] * rsqrtf(bnv[layer * DD + c] + 1e-5f);
    float B = fmaf(b1[layer * DD + c] - bnm[layer * DD + c], A,
                   beta[layer * DD + c]);
    tileT[lane * DD + ((c + lane) & 63)] = fmaxf(fmaf(t[cc], A, B), 0.0f);
  }
  __syncthreads();

  #pragma unroll
  for (int cc = 0; cc < 16; ++cc) t[cc] = 0.0f;
  #pragma unroll 2
  for (int k = 0; k < DD; ++k) {
    float zk = tileT[lane * DD + ((k + lane) & 63)];
    #pragma unroll
    for (int cc = 0; cc < 16; ++cc)
      t[cc] = fmaf(zk, W2l[k * DD + c0 + cc], t[cc]);   // scalar W
  }
  #pragma unroll
  for (int cc = 0; cc < 16; ++cc) {
    int c = c0 + cc;
    tileZ[lane * DD + ((c + lane) & 63)] =
        fmaxf(t[cc] + b2[layer * DD + c], 0.0f);
  }
  __syncthreads();

  float accp = 0.0f;
  int gcur = -1;
  for (int i = 0; i < 16; ++i) {
    int r = c0 + i;
    int n = n0 + r;
    if (n >= N) break;
    float v = tileZ[r * DD + ((lane + r) & 63)];
    z[(size_t)n * DD + lane] = v;
    if (write_half) hhalf[(size_t)n * DD + lane] = __float2half(v);
    int g = batch[n];
    if (g != gcur) {
      if (gcur >= 0) atomicAdd(&hcat[gcur * HC + layer * 128 + lane], accp);
      gcur = g; accp = 0.0f;
    }
    accp = fmaf(v, pmask[n], accp);
  }
  if (gcur >= 0) atomicAdd(&hcat[gcur * HC + layer * 128 + lane], accp);
}

// ---------------- center-node gather (float4) ----------------
__global__ __launch_bounds__(256) void center_kernel(
    const float* __restrict__ h, const int* __restrict__ mapping,
    float* __restrict__ hcat, int layer, int G)
{
  int gid = blockIdx.x * 256 + threadIdx.x;
  int g = gid >> 4, q = (gid & 15) * 4;
  if (g >= G) return;
  float4 v = *(const float4*)(h + (size_t)mapping[g] * DD + q);
  *(float4*)(hcat + g * HC + layer * 128 + 64 + q) = v;
}

// ---------------- final linear ----------------
__global__ __launch_bounds__(256) void final_kernel(
    const float* __restrict__ hcat, const float* __restrict__ lw,
    const float* __restrict__ lb, float* __restrict__ out, int G)
{
  int gid = blockIdx.x * 256 + threadIdx.x;
  int g = gid >> 5, s = gid & 31;
  if (g >= G) return;
  float acc = lb[s];
  #pragma unroll 4
  for (int j = 0; j < HC; ++j)
    acc = fmaf(hcat[g * HC + j], lw[j * SS + s], acc);
  out[g * SS + s] = acc;
}

extern "C" void kernel_launch(void* const* d_in, const int* in_sizes, int n_in,
                              void* d_out, int out_size, void* d_ws, size_t ws_size,
                              hipStream_t stream)
{
  const float* x     = (const float*)d_in[0];
  const float* ew    = (const float*)d_in[1];
  const float* pmask = (const float*)d_in[2];
  const float* W1    = (const float*)d_in[3];
  const float* b1    = (const float*)d_in[4];
  const float* gma   = (const float*)d_in[5];
  const float* bta   = (const float*)d_in[6];
  const float* bnm   = (const float*)d_in[7];
  const float* bnv   = (const float*)d_in[8];
  const float* W2    = (const float*)d_in[9];
  const float* b2    = (const float*)d_in[10];
  const float* epsv  = (const float*)d_in[11];
  const float* lw    = (const float*)d_in[12];
  const float* lb    = (const float*)d_in[13];
  const int*   ei    = (const int*)d_in[14];
  const int*   batch = (const int*)d_in[15];
  const int*   mapping = (const int*)d_in[16];

  const int N = in_sizes[2];
  const int E = in_sizes[1];
  const int G = in_sizes[16];
  const int nbins = (N + BINW - 1) / BINW;      // <= 256 for this problem
  const int nchunks = (E + CHUNK - 1) / CHUNK;

  float*  bufA = (float*)d_ws;                        // N*DD
  float*  bufB = bufA + (size_t)N * DD;               // N*DD
  float*  hcat = bufB + (size_t)N * DD;               // G*HC
  int*    off  = (int*)(hcat + (size_t)G * HC);       // N+1
  int*    bin_cnt  = off + (N + 1);                   // 256
  int*    bin_base = bin_cnt + 256;                   // 257
  int*    bin_cur  = bin_base + 257;                  // 257 (pad to even)
  int2*   packed = (int2*)(bin_cur + 258);            // E
  __half* hhalf  = (__half*)(packed + (size_t)E);     // N*DD
  // ebin arrays alias bufB (only live during CSR build, before bufB's
  // first use at layer-1 gather)
  int*  ebin_dst = (int*)bufB;                        // E
  int2* ebin_sw  = (int2*)(ebin_dst + E);             // E
  float* fout = (float*)d_out;

  // ---- CSR build ----
  hipMemsetAsync(bin_cnt, 0, 256 * sizeof(int), stream);
  bin_count_kernel<<<256, 256, 0, stream>>>(ei, bin_cnt, E);
  bin_scan_kernel<<<1, 256, 0, stream>>>(bin_cnt, bin_base, bin_cur, nbins);
  bin_part_kernel<<<nchunks, 256, 0, stream>>>(ei, ew, bin_cur,
                                               ebin_dst, ebin_sw, E);
  fine_csr_kernel<<<nbins, 256, 0, stream>>>(ebin_dst, ebin_sw, bin_base,
                                             off, packed, N, E);

  hipMemsetAsync(hcat, 0, (size_t)G * HC * sizeof(float), stream);
  tohalf_kernel<<<(N * DD / 8 + 255) / 256, 256, 0, stream>>>(x, hhalf, N * DD);

  // ---- 3 GIN layers ----
  const float* hsrc = x;
  float* zbuf = bufA;
  for (int layer = 0; layer < 3; ++layer) {
    gather_kernel<<<(N + 3) / 4, 256, 0, stream>>>(
        hhalf, hsrc, packed, off, epsv, zbuf, layer, N);
    node_kernel<<<(N + 63) / 64, 256, 0, stream>>>(
        zbuf, hhalf, W1, b1, gma, bta, bnm, bnv, W2, b2,
        pmask, batch, hcat, layer, N, (layer < 2) ? 1 : 0);
    center_kernel<<<(G * DD / 4 + 255) / 256, 256, 0, stream>>>(
        zbuf, mapping, hcat, layer, G);
    hsrc = zbuf;
    zbuf = (zbuf == bufA) ? bufB : bufA;
  }
  final_kernel<<<(G * SS + 255) / 256, 256, 0, stream>>>(hcat, lw, lb, fout, G);
}